// Round 1
// baseline (345.252 us; speedup 1.0000x reference)
//
#include <hip/hip_runtime.h>
#include <hip/hip_cooperative_groups.h>

namespace cg = cooperative_groups;

#define BS   256
#define GRID 1024   // launched blocks: 4/CU on 256 CUs, trivially co-resident
#define VNB  2048   // virtual reduction-partial count (bit-exact vs prior 3-kernel version)
#define NB3  2048   // fallback add blocks

typedef float vfloat4 __attribute__((ext_vector_type(4)));

// ---------------- fused cooperative kernel ----------------
// Phase 1: weighted column partial sums (2 virtual blocks per real block,
//          identical summation order to the old 2048-block reduce_kernel).
// grid.sync()
// Phase 2: every block redundantly reduces the 2048 partials + tiny MLP
//          (identical op order to old middle_kernel -> bit-identical r).
// Phase 3: out[i][j] = x[i][j] + r[j], NT stores (x re-read is L3-warm).
__global__ void __launch_bounds__(BS) fused_kernel(
    const float* __restrict__ x, const float* __restrict__ w,
    const float* __restrict__ W_in, const float* __restrict__ W_out,
    float* __restrict__ out, float* __restrict__ colpart,
    float* __restrict__ wpart, long long total4) {
  const int tid = threadIdx.x;
  __shared__ vfloat4 sacc[BS];
  __shared__ float   swr[BS];
  __shared__ float   avg[32];
  __shared__ float   h[128];
  __shared__ __align__(16) float sr[32];

  // ---- Phase 1 ----
  {
    const vfloat4* x4 = (const vfloat4*)x;
    const long long stride2 = (long long)VNB * (2 * BS);  // virtual-grid stride
    for (int half = 0; half < 2; ++half) {
      const int vb = (int)blockIdx.x + half * GRID;
      vfloat4 a0 = (vfloat4)(0.f), a1 = (vfloat4)(0.f);
      float w0 = 0.f, w1 = 0.f;
      long long c = (long long)vb * (2 * BS) + tid;
      for (; c + BS < total4; c += stride2) {
        const float wi0 = w[(int)(c >> 3)];
        const float wi1 = w[(int)((c + BS) >> 3)];
        const vfloat4 v0 = x4[c];
        const vfloat4 v1 = x4[c + BS];
        a0 += wi0 * v0;
        a1 += wi1 * v1;
        w0 += wi0; w1 += wi1;
      }
      if (c < total4) {  // tail: lone chunk without an in-range partner
        const float wi = w[(int)(c >> 3)];
        a0 += wi * x4[c];
        w0 += wi;
      }
      a0 += a1;
      w0 += w1;
      __syncthreads();  // protect LDS reuse across halves (epilogue readers)
      sacc[tid] = a0;
      swr[tid]  = w0;
      __syncthreads();
      for (int s = BS / 2; s >= 8; s >>= 1) {
        if (tid < s) { sacc[tid] += sacc[tid + s]; swr[tid] += swr[tid + s]; }
        __syncthreads();
      }
      if (tid < 8) {
        ((vfloat4*)(colpart + (long long)vb * 32))[tid] = sacc[tid];
      }
      if (tid == 0) {
        wpart[vb] = swr[0] + swr[1] + swr[2] + swr[3] +
                    swr[4] + swr[5] + swr[6] + swr[7];
      }
    }
  }

  cg::this_grid().sync();  // release/acquire at agent scope: partials visible

  // ---- Phase 2 (redundant per block; bit-identical to old middle_kernel) ----
  {
    const vfloat4* cp4 = (const vfloat4*)colpart;
    vfloat4 acc = (vfloat4)(0.f);
    for (int cb = tid; cb < VNB * 8; cb += BS) acc += cp4[cb];
    sacc[tid] = acc;
    {
      const vfloat4* wp4 = (const vfloat4*)wpart;
      float s = 0.f;
      for (int cb = tid; cb < VNB / 4; cb += BS) {
        vfloat4 v = wp4[cb];
        s += v.x + v.y + v.z + v.w;
      }
      swr[tid] = s;
    }
    __syncthreads();
    for (int s = BS / 2; s >= 8; s >>= 1) {
      if (tid < s) { sacc[tid] += sacc[tid + s]; swr[tid] += swr[tid + s]; }
      __syncthreads();
    }
    if (tid == 0) {
      // wpart counted each w 8x (once per chunk) -> *0.125 (exact)
      swr[0] = (swr[0] + swr[1] + swr[2] + swr[3] +
                swr[4] + swr[5] + swr[6] + swr[7]) * 0.125f;
    }
    __syncthreads();
    if (tid < 32) {
      const float* sflat = (const float*)sacc;
      avg[tid] = sflat[tid] / swr[0];
    }
    __syncthreads();
    if (tid < 128) {
      float a = 0.f;
      for (int k = 0; k < 32; ++k) a = fmaf(W_in[tid * 32 + k], avg[k], a);
      h[tid] = fmaxf(a, 0.f);
    }
    __syncthreads();
    if (tid < 32) {
      float rv = 0.f;
      for (int k = 0; k < 128; ++k) rv = fmaf(W_out[tid * 128 + k], h[k], rv);
      sr[tid] = rv;
    }
    __syncthreads();
  }

  // ---- Phase 3: out = x + r ----
  {
    const vfloat4 rr = ((const vfloat4*)sr)[tid & 7];  // chunk col-quad == tid&7
    const long long stride2 = (long long)GRID * (2 * BS);
    const vfloat4* x4 = (const vfloat4*)x;
    vfloat4* o4 = (vfloat4*)out;
    long long c = (long long)blockIdx.x * (2 * BS) + tid;
    for (; c + BS < total4; c += stride2) {
      vfloat4 v0 = x4[c] + rr;
      vfloat4 v1 = x4[c + BS] + rr;
      __builtin_nontemporal_store(v0, &o4[c]);
      __builtin_nontemporal_store(v1, &o4[c + BS]);
    }
    if (c < total4) {
      vfloat4 v = x4[c] + rr;
      __builtin_nontemporal_store(v, &o4[c]);
    }
  }
}

// ---------------- fallback path (previous proven 3-kernel version) ----------------
__global__ void __launch_bounds__(BS) reduce_kernel(
    const float* __restrict__ x, const float* __restrict__ w,
    float* __restrict__ colpart, float* __restrict__ wpart, long long total4) {
  const int tid = threadIdx.x;
  const long long stride2 = (long long)gridDim.x * (2 * BS);
  const vfloat4* x4 = (const vfloat4*)x;
  vfloat4 a0 = (vfloat4)(0.f);
  vfloat4 a1 = (vfloat4)(0.f);
  float w0 = 0.f, w1 = 0.f;
  long long c = (long long)blockIdx.x * (2 * BS) + tid;
  for (; c + BS < total4; c += stride2) {
    const float wi0 = w[(int)(c >> 3)];
    const float wi1 = w[(int)((c + BS) >> 3)];
    const vfloat4 v0 = x4[c];
    const vfloat4 v1 = x4[c + BS];
    a0 += wi0 * v0;
    a1 += wi1 * v1;
    w0 += wi0; w1 += wi1;
  }
  if (c < total4) {
    const float wi = w[(int)(c >> 3)];
    a0 += wi * x4[c];
    w0 += wi;
  }
  a0 += a1;
  w0 += w1;
  __shared__ vfloat4 sacc[BS];
  __shared__ float   sw[BS];
  sacc[tid] = a0;
  sw[tid] = w0;
  __syncthreads();
  for (int s = BS / 2; s >= 8; s >>= 1) {
    if (tid < s) { sacc[tid] += sacc[tid + s]; sw[tid] += sw[tid + s]; }
    __syncthreads();
  }
  if (tid < 8) ((vfloat4*)(colpart + (long long)blockIdx.x * 32))[tid] = sacc[tid];
  if (tid == 0)
    wpart[blockIdx.x] = sw[0] + sw[1] + sw[2] + sw[3] + sw[4] + sw[5] + sw[6] + sw[7];
}

__global__ void __launch_bounds__(BS) middle_kernel(
    const float* __restrict__ colpart, const float* __restrict__ wpart,
    const float* __restrict__ W_in, const float* __restrict__ W_out,
    float* __restrict__ r_out, int nb) {
  const int tid = threadIdx.x;
  __shared__ vfloat4 sacc[BS];
  __shared__ float   swr[BS];
  __shared__ float   avg[32];
  __shared__ float   h[128];
  {
    const vfloat4* cp4 = (const vfloat4*)colpart;
    const int nchunk = nb * 8;
    vfloat4 acc = (vfloat4)(0.f);
    for (int cb = tid; cb < nchunk; cb += BS) acc += cp4[cb];
    sacc[tid] = acc;
  }
  {
    const vfloat4* wp4 = (const vfloat4*)wpart;
    const int nchunk = nb / 4;
    float s = 0.f;
    for (int cb = tid; cb < nchunk; cb += BS) {
      vfloat4 v = wp4[cb];
      s += v.x + v.y + v.z + v.w;
    }
    swr[tid] = s;
  }
  __syncthreads();
  for (int s = BS / 2; s >= 8; s >>= 1) {
    if (tid < s) { sacc[tid] += sacc[tid + s]; swr[tid] += swr[tid + s]; }
    __syncthreads();
  }
  if (tid == 0) {
    swr[0] = (swr[0] + swr[1] + swr[2] + swr[3] +
              swr[4] + swr[5] + swr[6] + swr[7]) * 0.125f;
  }
  __syncthreads();
  if (tid < 32) {
    const float* sflat = (const float*)sacc;
    avg[tid] = sflat[tid] / swr[0];
  }
  __syncthreads();
  if (tid < 128) {
    float a = 0.f;
    for (int k = 0; k < 32; ++k) a = fmaf(W_in[tid * 32 + k], avg[k], a);
    h[tid] = fmaxf(a, 0.f);
  }
  __syncthreads();
  if (tid < 32) {
    float r = 0.f;
    for (int k = 0; k < 128; ++k) r = fmaf(W_out[tid * 128 + k], h[k], r);
    r_out[tid] = r;
  }
}

__global__ void __launch_bounds__(BS) add_kernel(
    const float* __restrict__ x, const float* __restrict__ r,
    float* __restrict__ out, long long total4) {
  const int tid = threadIdx.x;
  const vfloat4 rr = ((const vfloat4*)r)[tid & 7];
  const long long stride2 = (long long)gridDim.x * (2 * BS);
  const vfloat4* x4 = (const vfloat4*)x;
  vfloat4* o4 = (vfloat4*)out;
  long long c = (long long)blockIdx.x * (2 * BS) + tid;
  for (; c + BS < total4; c += stride2) {
    vfloat4 v0 = x4[c] + rr;
    vfloat4 v1 = x4[c + BS] + rr;
    __builtin_nontemporal_store(v0, &o4[c]);
    __builtin_nontemporal_store(v1, &o4[c + BS]);
  }
  if (c < total4) {
    vfloat4 v = x4[c] + rr;
    __builtin_nontemporal_store(v, &o4[c]);
  }
}

extern "C" void kernel_launch(void* const* d_in, const int* in_sizes, int n_in,
                              void* d_out, int out_size, void* d_ws, size_t ws_size,
                              hipStream_t stream) {
  const float* x     = (const float*)d_in[0];
  const float* w     = (const float*)d_in[1];
  const float* W_in  = (const float*)d_in[2];
  const float* W_out = (const float*)d_in[3];
  float* out = (float*)d_out;

  const long long N = (long long)in_sizes[0] / 32;
  const long long total4 = N * 8;  // float4 chunks (32 floats/row = 8 float4)

  // workspace layout: colpart[VNB*32] | wpart[VNB] | r[32]  (~270 KB)
  float* colpart = (float*)d_ws;
  float* wpart   = colpart + (size_t)VNB * 32;
  float* r       = wpart + VNB;

  if ((size_t)(VNB * 33 + 32) * 4 <= ws_size) {
    void* args[] = {(void*)&x, (void*)&w, (void*)&W_in, (void*)&W_out,
                    (void*)&out, (void*)&colpart, (void*)&wpart, (void*)&total4};
    hipError_t err = hipLaunchCooperativeKernel((const void*)fused_kernel,
                                                dim3(GRID), dim3(BS), args, 0, stream);
    if (err == hipSuccess) return;
  }

  // fallback: proven 3-kernel path
  int nb = VNB;
  while (nb > 64 && (size_t)(nb * 33 + 32) * 4 > ws_size) nb >>= 1;
  reduce_kernel<<<nb, BS, 0, stream>>>(x, w, colpart, wpart, total4);
  middle_kernel<<<1, BS, 0, stream>>>(colpart, wpart, W_in, W_out, r, nb);
  add_kernel<<<NB3, BS, 0, stream>>>(x, r, out, total4);
}